// Round 14
// baseline (102.703 us; speedup 1.0000x reference)
//
#include <hip/hip_runtime.h>
#include <stdint.h>

// ---------------------------------------------------------------------------
// Bottleneck with 3x3 local self-attention, MI355X (gfx950).
// R14: vectorize the prep transpose (was scalar 2B stores / 4B loads -> G13
// violation): f32x4 loads, u16x4 packed stores, 1 iter/thread. Bank-free
// ([32][33] tile, <=2-way both sides). Everything else = R13 best-known.
// Layout: activations (pix, C) bf16; 1x1 conv = gemm_bt:
//   D[o][P] = sum_k A[o][k]*B[P][k], MFMA 16x16x32 bf16.
// ---------------------------------------------------------------------------

typedef __attribute__((ext_vector_type(4))) float f32x4;
typedef __attribute__((ext_vector_type(8))) __bf16 bf16x8;
typedef __attribute__((ext_vector_type(4))) unsigned short u16x4;
typedef __attribute__((ext_vector_type(8))) unsigned short u16x8;

__device__ __forceinline__ float bf2f(unsigned short u) {
  union { unsigned int i; float f; } c; c.i = ((unsigned int)u) << 16; return c.f;
}
__device__ __forceinline__ unsigned short f2bf(float f) {
  union { float f; unsigned int i; } c; c.f = f;
  unsigned int x = c.i;
  return (unsigned short)((x + 0x7FFFu + ((x >> 16) & 1u)) >> 16);
}
__device__ __forceinline__ void gload_lds16(const unsigned short* g, unsigned short* l) {
  __builtin_amdgcn_global_load_lds(
      (const __attribute__((address_space(1))) unsigned int*)(const void*)g,
      (__attribute__((address_space(3))) unsigned int*)(void*)l, 16, 0, 0);
}

// ---------------------------------------------------------------------------
// Merged prep: blocks [0,16384) transpose x -> xt (vectorized); rest convert
// weights + stack qkv bn params.
__global__ __launch_bounds__(256) void k_prep(
    const float* __restrict__ x, unsigned short* __restrict__ xt,
    const float* __restrict__ w1, const float* __restrict__ wq,
    const float* __restrict__ wk, const float* __restrict__ wv,
    const float* __restrict__ w3,
    const float* __restrict__ sq, const float* __restrict__ sk,
    const float* __restrict__ sv, const float* __restrict__ bq,
    const float* __restrict__ bk, const float* __restrict__ bv,
    unsigned short* __restrict__ w1b, unsigned short* __restrict__ wqkvb,
    unsigned short* __restrict__ w3b, float* __restrict__ sqkv,
    float* __restrict__ bqkv) {
  const int bid = blockIdx.x;
  if (bid < 16384) {
    // transpose: x (16,1024c,1024p) f32 -> xt (16,1024p,1024c) bf16
    __shared__ float tile[32][33];
    const int p0 = (bid & 31) * 32;
    const int c0 = ((bid >> 5) & 31) * 32;
    const int b  = bid >> 10;
    const float* xb = x + (size_t)b * 1048576;
    unsigned short* xtb = xt + (size_t)b * 1048576;
    const int tr = threadIdx.x >> 3;   // 0..31
    const int tg = threadIdx.x & 7;    // 0..7
    // load: 32c x 32p tile, one f32x4 per thread (128B/8-lane segment)
    *(f32x4*)&tile[tr][tg * 4] =
        *(const f32x4*)&xb[(size_t)(c0 + tr) * 1024 + p0 + tg * 4];
    __syncthreads();
    // store: P = tr, c-group tg (4 c each); stride-33 LDS reads (<=2-way)
    u16x4 pk;
#pragma unroll
    for (int e = 0; e < 4; ++e) pk[e] = f2bf(tile[tg * 4 + e][tr]);
    *(u16x4*)&xtb[(size_t)(p0 + tr) * 1024 + c0 + tg * 4] = pk;
    return;
  }
  const int idx = (bid - 16384) * 256 + threadIdx.x;
  if (idx < 262144) { w1b[idx] = f2bf(w1[idx]); return; }
  if (idx < 327680) { wqkvb[idx - 262144] = f2bf(wq[idx - 262144]); return; }
  if (idx < 393216) { wqkvb[idx - 262144] = f2bf(wk[idx - 327680]); return; }
  if (idx < 458752) { wqkvb[idx - 262144] = f2bf(wv[idx - 393216]); return; }
  if (idx < 720896) { w3b[idx - 458752] = f2bf(w3[idx - 458752]); return; }
  if (idx < 721664) {
    const int i = idx - 720896;
    sqkv[i] = i < 256 ? sq[i] : (i < 512 ? sk[i - 256] : sv[i - 512]);
    return;
  }
  if (idx < 722432) {
    const int i = idx - 721664;
    bqkv[i] = i < 256 ? bq[i] : (i < 512 ? bk[i - 256] : bv[i - 512]);
  }
}

// ---------------------------------------------------------------------------
// Generic all-bf16 gemm_bt, 2-phase pipelined, 1D grid with XCD chunking.
// Flatten x-major; bijective 8-way chunk: swz = (bid&7)*(nwg/8) + bid>>3;
// bx = swz/gy (n), by = swz%gy (m). Wave tile MF*16 x NF*16; 2x2 waves.
// Per K-step: STAGE(buf[p^1]) first, ds_read+MFMA on buf[p], ONE barrier.
// Source col-group pre-swizzled by ^(row&3); read with cg = fq^(fr&3).
// MODE 0: Cout u16 pix-major: idx=(og>>8)*4194304 + P*256 + (og&255);
//         relu iff (relu_mask>>(og>>8))&1.
// MODE 1: Cout f32 d_out[b][o][pix] = relu(acc*s+b+resid); resid = xt bf16
//         P-major, loaded packed AFTER the K-loop.
template <int MF, int NF, int MODE>
__global__ __launch_bounds__(256, 3) void k_gemm_bt(
    const unsigned short* __restrict__ A, const unsigned short* __restrict__ B,
    void* __restrict__ CoutV, const float* __restrict__ scale,
    const float* __restrict__ bias, const unsigned short* __restrict__ resid_bf,
    int K, int relu_mask, int gy) {
  constexpr int BM = MF * 32, BN = NF * 32;
  __shared__ unsigned short lA[2][BM * 32];
  __shared__ unsigned short lB[2][BN * 32];
  const int nwg = gridDim.x;
  const int bid = blockIdx.x;
  const int swz = (bid & 7) * (nwg >> 3) + (bid >> 3);
  const int bx = swz / gy, by = swz - bx * gy;
  const int m0 = by * BM;
  const int n0 = bx * BN;
  const int tid = threadIdx.x;
  const int lane = tid & 63, wid = tid >> 6;
  const int wm = (wid >> 1) * (MF * 16), wn = (wid & 1) * (NF * 16);
  const int fr = lane & 15, fq = lane >> 4;
  const int cgr = (fq ^ (fr & 3)) * 8;   // swizzled read col offset (elems)

  f32x4 acc[MF][NF] = {};

  const int sr  = lane >> 2;
  const int scg = ((lane & 3) ^ (sr & 3)) * 8;
  const int warA = wid * (MF * 8);
  const int warB = wid * (NF * 8);
  const unsigned short* Asrc = A + (size_t)(m0 + warA + sr) * K + scg;
  const unsigned short* Bsrc = B + (size_t)(n0 + warB + sr) * K + scg;

  // prologue: stage k0=0 into buf 0
#pragma unroll
  for (int u = 0; u < MF / 2; ++u)
    gload_lds16(Asrc + (size_t)u * 16 * K, &lA[0][(warA + u * 16) * 32]);
#pragma unroll
  for (int u = 0; u < NF / 2; ++u)
    gload_lds16(Bsrc + (size_t)u * 16 * K, &lB[0][(warB + u * 16) * 32]);
  __syncthreads();

  int p = 0;
  for (int k0 = 0; k0 < K; k0 += 32) {
    if (k0 + 32 < K) {  // stage next tile; loads fly during compute below
#pragma unroll
      for (int u = 0; u < MF / 2; ++u)
        gload_lds16(Asrc + (size_t)u * 16 * K + k0 + 32, &lA[p ^ 1][(warA + u * 16) * 32]);
#pragma unroll
      for (int u = 0; u < NF / 2; ++u)
        gload_lds16(Bsrc + (size_t)u * 16 * K + k0 + 32, &lB[p ^ 1][(warB + u * 16) * 32]);
    }

    bf16x8 af[MF], bb[NF];
#pragma unroll
    for (int i = 0; i < MF; ++i)
      af[i] = *(const bf16x8*)&lA[p][(wm + i * 16 + fr) * 32 + cgr];
#pragma unroll
    for (int j = 0; j < NF; ++j)
      bb[j] = *(const bf16x8*)&lB[p][(wn + j * 16 + fr) * 32 + cgr];
#pragma unroll
    for (int i = 0; i < MF; ++i)
#pragma unroll
      for (int j = 0; j < NF; ++j)
        acc[i][j] = __builtin_amdgcn_mfma_f32_16x16x32_bf16(af[i], bb[j], acc[i][j], 0, 0, 0);

    __syncthreads();
    p ^= 1;
  }

  u16x4 rp[MF][NF];
  if (MODE == 1) {  // packed bf16 residual, loaded once after the K-loop
#pragma unroll
    for (int i = 0; i < MF; ++i) {
      const int og = m0 + wm + i * 16 + fq * 4;
#pragma unroll
      for (int j = 0; j < NF; ++j) {
        const int P = n0 + wn + j * 16 + fr;
        rp[i][j] = *(const u16x4*)&resid_bf[(size_t)P * 1024 + og];
      }
    }
  }

#pragma unroll
  for (int i = 0; i < MF; ++i) {
    const int og = m0 + wm + i * 16 + fq * 4;
    const f32x4 s4 = *(const f32x4*)&scale[og];
    const f32x4 b4 = *(const f32x4*)&bias[og];
#pragma unroll
    for (int j = 0; j < NF; ++j) {
      const int P = n0 + wn + j * 16 + fr;
      if (MODE == 0) {
        unsigned short* Cout = (unsigned short*)CoutV;
        const int do_relu = (relu_mask >> (og >> 8)) & 1;
        const size_t obase = (size_t)(og >> 8) * 4194304 + (size_t)P * 256 + (og & 255);
        u16x4 pk;
#pragma unroll
        for (int rr = 0; rr < 4; ++rr) {
          float v = acc[i][j][rr] * s4[rr] + b4[rr];
          if (do_relu) v = fmaxf(v, 0.0f);
          pk[rr] = f2bf(v);
        }
        *(u16x4*)&Cout[obase] = pk;
      } else {
        float* Cout = (float*)CoutV;
        const size_t base = (size_t)(P >> 10) * 1048576 + (size_t)(P & 1023);
#pragma unroll
        for (int rr = 0; rr < 4; ++rr) {
          float v = acc[i][j][rr] * s4[rr] + b4[rr] + bf2f(rp[i][j][rr]);
          Cout[base + (size_t)(og + rr) * 1024] = fmaxf(v, 0.0f);
        }
      }
    }
  }
}

// ---------------------------------------------------------------------------
// Local 3x3 attention. Thread = (pixel slot s=tid>>5, head g=tid&31).
__global__ __launch_bounds__(256, 4) void k_attn(
    const unsigned short* __restrict__ Q, const unsigned short* __restrict__ Kb,
    const unsigned short* __restrict__ Vb, unsigned short* __restrict__ O,
    const float* __restrict__ pos_h, const float* __restrict__ pos_w,
    const float* __restrict__ bs, const float* __restrict__ bb) {
  __shared__ float ph_l[3][256];
  __shared__ float pw_l[3][256];
  {
    const int c = threadIdx.x;
#pragma unroll
    for (int i = 0; i < 3; ++i) {
      ph_l[i][c] = pos_h[c * 3 + i];
      pw_l[i][c] = pos_w[c * 3 + i];
    }
  }
  __syncthreads();
  const int tid = threadIdx.x;
  const int g = tid & 31, s = tid >> 5;
  const int P = blockIdx.x * 8 + s;
  const int b = P >> 10, pix = P & 1023;
  const int hh = pix >> 5, ww = pix & 31;
  const int c0 = g * 8;

  float qf[8];
  {
    u16x8 qv = *(const u16x8*)&Q[(size_t)P * 256 + c0];
#pragma unroll
    for (int d = 0; d < 8; ++d) qf[d] = bf2f(qv[d]);
  }
  float Ai[3], Bj[3];
#pragma unroll
  for (int i = 0; i < 3; ++i) {
    float a = 0.f, w = 0.f;
#pragma unroll
    for (int d = 0; d < 8; ++d) {
      a += qf[d] * ph_l[i][c0 + d];
      w += qf[d] * pw_l[i][c0 + d];
    }
    Ai[i] = a; Bj[i] = w;
  }

  float S[9];
  int nPs[9];
#pragma unroll
  for (int t = 0; t < 9; ++t) {
    const int di = t / 3, dj = t % 3;
    const int nh = hh + di - 1, nw = ww + dj - 1;
    float sum = Ai[di] + Bj[dj];
    int nP = -1;
    if ((unsigned)nh < 32u && (unsigned)nw < 32u) {
      nP = (b << 10) + (nh << 5) + nw;
      u16x8 kv = *(const u16x8*)&Kb[(size_t)nP * 256 + c0];
#pragma unroll
      for (int d = 0; d < 8; ++d) sum += qf[d] * bf2f(kv[d]);
    }
    nPs[t] = nP;
    S[t] = sum;
  }

  float mx = S[0];
#pragma unroll
  for (int t = 1; t < 9; ++t) mx = fmaxf(mx, S[t]);
  float e[9], tot = 0.f;
#pragma unroll
  for (int t = 0; t < 9; ++t) { e[t] = __expf(S[t] - mx); tot += e[t]; }
  const float inv = 1.0f / tot;

  float of[8] = {0.f, 0.f, 0.f, 0.f, 0.f, 0.f, 0.f, 0.f};
#pragma unroll
  for (int t = 0; t < 9; ++t) {
    if (nPs[t] >= 0) {
      u16x8 vv = *(const u16x8*)&Vb[(size_t)nPs[t] * 256 + c0];
      const float w = e[t] * inv;
#pragma unroll
      for (int d = 0; d < 8; ++d) of[d] += w * bf2f(vv[d]);
    }
  }

  u16x8 res;
#pragma unroll
  for (int d = 0; d < 8; ++d) {
    float v = of[d] * bs[c0 + d] + bb[c0 + d];
    v = fmaxf(v, 0.0f);
    res[d] = f2bf(v);
  }
  *(u16x8*)&O[(size_t)P * 256 + c0] = res;
}

// ---------------------------------------------------------------------------
extern "C" void kernel_launch(void* const* d_in, const int* in_sizes, int n_in,
                              void* d_out, int out_size, void* d_ws, size_t ws_size,
                              hipStream_t stream) {
  (void)in_sizes; (void)n_in; (void)out_size; (void)ws_size;
  const float* x       = (const float*)d_in[0];
  const float* w1      = (const float*)d_in[1];
  const float* bn1_s   = (const float*)d_in[2];
  const float* bn1_b   = (const float*)d_in[3];
  const float* wq      = (const float*)d_in[4];
  const float* bnq_s   = (const float*)d_in[5];
  const float* bnq_b   = (const float*)d_in[6];
  const float* wk      = (const float*)d_in[7];
  const float* bnk_s   = (const float*)d_in[8];
  const float* bnk_b   = (const float*)d_in[9];
  const float* wv      = (const float*)d_in[10];
  const float* bnv_s   = (const float*)d_in[11];
  const float* bnv_b   = (const float*)d_in[12];
  const float* pos_h   = (const float*)d_in[13];
  const float* pos_w   = (const float*)d_in[14];
  const float* bnatt_s = (const float*)d_in[15];
  const float* bnatt_b = (const float*)d_in[16];
  const float* w3      = (const float*)d_in[17];
  const float* bn3_s   = (const float*)d_in[18];
  const float* bn3_b   = (const float*)d_in[19];

  char* ws = (char*)d_ws;
  unsigned short* h1t   = (unsigned short*)(ws);               // 8 MiB
  unsigned short* qkvt  = (unsigned short*)(ws + 8388608);     // 24 MiB (q|k|v)
  unsigned short* att   = (unsigned short*)(ws + 33554432);    // 8 MiB
  unsigned short* xt    = (unsigned short*)(ws + 41943040);    // 32 MiB
  unsigned short* w1b   = (unsigned short*)(ws + 75497472);    // 512 KiB
  unsigned short* wqkvb = (unsigned short*)(ws + 76021760);    // 384 KiB
  unsigned short* w3b   = (unsigned short*)(ws + 76414976);    // 512 KiB
  float*          sqkv  = (float*)(ws + 76939264);             // 3 KiB
  float*          bqkv  = (float*)(ws + 76942336);             // 3 KiB

  // prep: transpose (16384 blocks) + weight convert (2822 blocks)
  k_prep<<<dim3(19206), dim3(256), 0, stream>>>(
      x, xt, w1, wq, wk, wv, w3, bnq_s, bnk_s, bnv_s, bnq_b, bnk_b, bnv_b,
      w1b, wqkvb, w3b, sqkv, bqkv);

  // conv1: M=256, N=16384, K=1024; tile 128x64 -> nwg=512, gy=2
  k_gemm_bt<4, 2, 0><<<dim3(512), dim3(256), 0, stream>>>(
      w1b, xt, h1t, bn1_s, bn1_b, nullptr, 1024, 1, 2);

  // fused qkv: stacked A (768x256); tile 128x128 -> nwg=768, gy=6
  k_gemm_bt<4, 4, 0><<<dim3(768), dim3(256), 0, stream>>>(
      wqkvb, h1t, qkvt, sqkv, bqkv, nullptr, 256, 3, 6);

  k_attn<<<dim3(2048), dim3(256), 0, stream>>>(
      qkvt, qkvt + 4194304, qkvt + 8388608, att, pos_h, pos_w, bnatt_s, bnatt_b);

  // conv3 + residual(bf16 from xt) + relu -> d_out (f32); tile 128x128
  // -> nwg=1024, gy=8
  k_gemm_bt<4, 4, 1><<<dim3(1024), dim3(256), 0, stream>>>(
      w3b, att, d_out, bn3_s, bn3_b, xt, 256, 0, 8);
}

// Round 15
// 99.454 us; speedup vs baseline: 1.0327x; 1.0327x over previous
//
#include <hip/hip_runtime.h>
#include <stdint.h>

// ---------------------------------------------------------------------------
// Bottleneck with 3x3 local self-attention, MI355X (gfx950).
// R15: BK as template param; conv1 runs BK=64 (16 barriers instead of 32 —
// the K=1024 barrier chain was the last model-visible overhead). KB=32 path
// is bit-identical to R13/R14 proven code; qkv/conv3 unchanged.
// Layout: activations (pix, C) bf16; 1x1 conv = gemm_bt:
//   D[o][P] = sum_k A[o][k]*B[P][k], MFMA 16x16x32 bf16.
// ---------------------------------------------------------------------------

typedef __attribute__((ext_vector_type(4))) float f32x4;
typedef __attribute__((ext_vector_type(8))) __bf16 bf16x8;
typedef __attribute__((ext_vector_type(4))) unsigned short u16x4;
typedef __attribute__((ext_vector_type(8))) unsigned short u16x8;

__device__ __forceinline__ float bf2f(unsigned short u) {
  union { unsigned int i; float f; } c; c.i = ((unsigned int)u) << 16; return c.f;
}
__device__ __forceinline__ unsigned short f2bf(float f) {
  union { float f; unsigned int i; } c; c.f = f;
  unsigned int x = c.i;
  return (unsigned short)((x + 0x7FFFu + ((x >> 16) & 1u)) >> 16);
}
__device__ __forceinline__ void gload_lds16(const unsigned short* g, unsigned short* l) {
  __builtin_amdgcn_global_load_lds(
      (const __attribute__((address_space(1))) unsigned int*)(const void*)g,
      (__attribute__((address_space(3))) unsigned int*)(void*)l, 16, 0, 0);
}

// ---------------------------------------------------------------------------
// Merged prep: blocks [0,16384) transpose x -> xt (vectorized); rest convert
// weights + stack qkv bn params.
__global__ __launch_bounds__(256) void k_prep(
    const float* __restrict__ x, unsigned short* __restrict__ xt,
    const float* __restrict__ w1, const float* __restrict__ wq,
    const float* __restrict__ wk, const float* __restrict__ wv,
    const float* __restrict__ w3,
    const float* __restrict__ sq, const float* __restrict__ sk,
    const float* __restrict__ sv, const float* __restrict__ bq,
    const float* __restrict__ bk, const float* __restrict__ bv,
    unsigned short* __restrict__ w1b, unsigned short* __restrict__ wqkvb,
    unsigned short* __restrict__ w3b, float* __restrict__ sqkv,
    float* __restrict__ bqkv) {
  const int bid = blockIdx.x;
  if (bid < 16384) {
    __shared__ float tile[32][33];
    const int p0 = (bid & 31) * 32;
    const int c0 = ((bid >> 5) & 31) * 32;
    const int b  = bid >> 10;
    const float* xb = x + (size_t)b * 1048576;
    unsigned short* xtb = xt + (size_t)b * 1048576;
    const int tr = threadIdx.x >> 3;   // 0..31
    const int tg = threadIdx.x & 7;    // 0..7
    *(f32x4*)&tile[tr][tg * 4] =
        *(const f32x4*)&xb[(size_t)(c0 + tr) * 1024 + p0 + tg * 4];
    __syncthreads();
    u16x4 pk;
#pragma unroll
    for (int e = 0; e < 4; ++e) pk[e] = f2bf(tile[tg * 4 + e][tr]);
    *(u16x4*)&xtb[(size_t)(p0 + tr) * 1024 + c0 + tg * 4] = pk;
    return;
  }
  const int idx = (bid - 16384) * 256 + threadIdx.x;
  if (idx < 262144) { w1b[idx] = f2bf(w1[idx]); return; }
  if (idx < 327680) { wqkvb[idx - 262144] = f2bf(wq[idx - 262144]); return; }
  if (idx < 393216) { wqkvb[idx - 262144] = f2bf(wk[idx - 327680]); return; }
  if (idx < 458752) { wqkvb[idx - 262144] = f2bf(wv[idx - 393216]); return; }
  if (idx < 720896) { w3b[idx - 458752] = f2bf(w3[idx - 458752]); return; }
  if (idx < 721664) {
    const int i = idx - 720896;
    sqkv[i] = i < 256 ? sq[i] : (i < 512 ? sk[i - 256] : sv[i - 512]);
    return;
  }
  if (idx < 722432) {
    const int i = idx - 721664;
    bqkv[i] = i < 256 ? bq[i] : (i < 512 ? bk[i - 256] : bv[i - 512]);
  }
}

// ---------------------------------------------------------------------------
// Generic all-bf16 gemm_bt, 2-phase pipelined, 1D grid with XCD chunking,
// parametric K-step KB (32 or 64). CG = KB/8 col-groups of 8 elems.
// Staging: lane -> row sr = lane/(KB/8), group lg = lane%(KB/8); source
// col-group pre-swizzled by ^(sr & (CG-1)); LDS dest linear (gload_lds).
// Fragment read: cg = (ks*4+fq) ^ (row & (CG-1)) (involution matches).
// Per K-step: GA+GB gload_lds, (MF+NF)*KB/32 ds_read_b128, MF*NF*KB/32 MFMA,
// ONE barrier. KB=64 halves the barrier count for K=1024.
// MODE 0: Cout u16 pix-major: idx=(og>>8)*4194304 + P*256 + (og&255);
//         relu iff (relu_mask>>(og>>8))&1.
// MODE 1: Cout f32 d_out[b][o][pix] = relu(acc*s+b+resid); resid = xt bf16
//         P-major, loaded packed AFTER the K-loop.
template <int MF, int NF, int MODE, int KB>
__global__ __launch_bounds__(256, 3) void k_gemm_bt(
    const unsigned short* __restrict__ A, const unsigned short* __restrict__ B,
    void* __restrict__ CoutV, const float* __restrict__ scale,
    const float* __restrict__ bias, const unsigned short* __restrict__ resid_bf,
    int K, int relu_mask, int gy) {
  constexpr int BM = MF * 32, BN = NF * 32;
  constexpr int CG = KB / 8;          // col-groups per row
  constexpr int RPG = 512 / KB;       // rows per gload_lds (wave covers 512 elems)
  constexpr int GA = (MF * 8) / RPG;  // gloads per wave, A
  constexpr int GB = (NF * 8) / RPG;  // gloads per wave, B
  constexpr int KS = KB / 32;         // MFMA k-sub-steps per K-step
  __shared__ unsigned short lA[2][BM * KB];
  __shared__ unsigned short lB[2][BN * KB];
  const int nwg = gridDim.x;
  const int bid = blockIdx.x;
  const int swz = (bid & 7) * (nwg >> 3) + (bid >> 3);
  const int bx = swz / gy, by = swz - bx * gy;
  const int m0 = by * BM;
  const int n0 = bx * BN;
  const int tid = threadIdx.x;
  const int lane = tid & 63, wid = tid >> 6;
  const int wm = (wid >> 1) * (MF * 16), wn = (wid & 1) * (NF * 16);
  const int fr = lane & 15, fq = lane >> 4;

  f32x4 acc[MF][NF] = {};

  const int sr = lane / (KB / 8);
  const int lg = lane & (CG - 1);
  const int scg = (lg ^ (sr & (CG - 1))) * 8;
  const int warA = wid * (MF * 8);
  const int warB = wid * (NF * 8);
  const unsigned short* Asrc = A + (size_t)(m0 + warA + sr) * K + scg;
  const unsigned short* Bsrc = B + (size_t)(n0 + warB + sr) * K + scg;

  // prologue: stage k0=0 into buf 0
#pragma unroll
  for (int u = 0; u < GA; ++u)
    gload_lds16(Asrc + (size_t)u * RPG * K, &lA[0][(warA + u * RPG) * KB]);
#pragma unroll
  for (int u = 0; u < GB; ++u)
    gload_lds16(Bsrc + (size_t)u * RPG * K, &lB[0][(warB + u * RPG) * KB]);
  __syncthreads();

  int p = 0;
  for (int k0 = 0; k0 < K; k0 += KB) {
    if (k0 + KB < K) {  // stage next tile; loads fly during compute below
#pragma unroll
      for (int u = 0; u < GA; ++u)
        gload_lds16(Asrc + (size_t)u * RPG * K + k0 + KB, &lA[p ^ 1][(warA + u * RPG) * KB]);
#pragma unroll
      for (int u = 0; u < GB; ++u)
        gload_lds16(Bsrc + (size_t)u * RPG * K + k0 + KB, &lB[p ^ 1][(warB + u * RPG) * KB]);
    }

    bf16x8 af[MF][KS], bb[NF][KS];
#pragma unroll
    for (int i = 0; i < MF; ++i) {
      const int row = wm + i * 16 + fr;
#pragma unroll
      for (int ks = 0; ks < KS; ++ks)
        af[i][ks] = *(const bf16x8*)&lA[p][row * KB + (((ks * 4 + fq) ^ (row & (CG - 1))) * 8)];
    }
#pragma unroll
    for (int j = 0; j < NF; ++j) {
      const int row = wn + j * 16 + fr;
#pragma unroll
      for (int ks = 0; ks < KS; ++ks)
        bb[j][ks] = *(const bf16x8*)&lB[p][row * KB + (((ks * 4 + fq) ^ (row & (CG - 1))) * 8)];
    }
#pragma unroll
    for (int ks = 0; ks < KS; ++ks)
#pragma unroll
      for (int i = 0; i < MF; ++i)
#pragma unroll
        for (int j = 0; j < NF; ++j)
          acc[i][j] = __builtin_amdgcn_mfma_f32_16x16x32_bf16(af[i][ks], bb[j][ks], acc[i][j], 0, 0, 0);

    __syncthreads();
    p ^= 1;
  }

  u16x4 rp[MF][NF];
  if (MODE == 1) {  // packed bf16 residual, loaded once after the K-loop
#pragma unroll
    for (int i = 0; i < MF; ++i) {
      const int og = m0 + wm + i * 16 + fq * 4;
#pragma unroll
      for (int j = 0; j < NF; ++j) {
        const int P = n0 + wn + j * 16 + fr;
        rp[i][j] = *(const u16x4*)&resid_bf[(size_t)P * 1024 + og];
      }
    }
  }

#pragma unroll
  for (int i = 0; i < MF; ++i) {
    const int og = m0 + wm + i * 16 + fq * 4;
    const f32x4 s4 = *(const f32x4*)&scale[og];
    const f32x4 b4 = *(const f32x4*)&bias[og];
#pragma unroll
    for (int j = 0; j < NF; ++j) {
      const int P = n0 + wn + j * 16 + fr;
      if (MODE == 0) {
        unsigned short* Cout = (unsigned short*)CoutV;
        const int do_relu = (relu_mask >> (og >> 8)) & 1;
        const size_t obase = (size_t)(og >> 8) * 4194304 + (size_t)P * 256 + (og & 255);
        u16x4 pk;
#pragma unroll
        for (int rr = 0; rr < 4; ++rr) {
          float v = acc[i][j][rr] * s4[rr] + b4[rr];
          if (do_relu) v = fmaxf(v, 0.0f);
          pk[rr] = f2bf(v);
        }
        *(u16x4*)&Cout[obase] = pk;
      } else {
        float* Cout = (float*)CoutV;
        const size_t base = (size_t)(P >> 10) * 1048576 + (size_t)(P & 1023);
#pragma unroll
        for (int rr = 0; rr < 4; ++rr) {
          float v = acc[i][j][rr] * s4[rr] + b4[rr] + bf2f(rp[i][j][rr]);
          Cout[base + (size_t)(og + rr) * 1024] = fmaxf(v, 0.0f);
        }
      }
    }
  }
}

// ---------------------------------------------------------------------------
// Local 3x3 attention. Thread = (pixel slot s=tid>>5, head g=tid&31).
__global__ __launch_bounds__(256, 4) void k_attn(
    const unsigned short* __restrict__ Q, const unsigned short* __restrict__ Kb,
    const unsigned short* __restrict__ Vb, unsigned short* __restrict__ O,
    const float* __restrict__ pos_h, const float* __restrict__ pos_w,
    const float* __restrict__ bs, const float* __restrict__ bb) {
  __shared__ float ph_l[3][256];
  __shared__ float pw_l[3][256];
  {
    const int c = threadIdx.x;
#pragma unroll
    for (int i = 0; i < 3; ++i) {
      ph_l[i][c] = pos_h[c * 3 + i];
      pw_l[i][c] = pos_w[c * 3 + i];
    }
  }
  __syncthreads();
  const int tid = threadIdx.x;
  const int g = tid & 31, s = tid >> 5;
  const int P = blockIdx.x * 8 + s;
  const int b = P >> 10, pix = P & 1023;
  const int hh = pix >> 5, ww = pix & 31;
  const int c0 = g * 8;

  float qf[8];
  {
    u16x8 qv = *(const u16x8*)&Q[(size_t)P * 256 + c0];
#pragma unroll
    for (int d = 0; d < 8; ++d) qf[d] = bf2f(qv[d]);
  }
  float Ai[3], Bj[3];
#pragma unroll
  for (int i = 0; i < 3; ++i) {
    float a = 0.f, w = 0.f;
#pragma unroll
    for (int d = 0; d < 8; ++d) {
      a += qf[d] * ph_l[i][c0 + d];
      w += qf[d] * pw_l[i][c0 + d];
    }
    Ai[i] = a; Bj[i] = w;
  }

  float S[9];
  int nPs[9];
#pragma unroll
  for (int t = 0; t < 9; ++t) {
    const int di = t / 3, dj = t % 3;
    const int nh = hh + di - 1, nw = ww + dj - 1;
    float sum = Ai[di] + Bj[dj];
    int nP = -1;
    if ((unsigned)nh < 32u && (unsigned)nw < 32u) {
      nP = (b << 10) + (nh << 5) + nw;
      u16x8 kv = *(const u16x8*)&Kb[(size_t)nP * 256 + c0];
#pragma unroll
      for (int d = 0; d < 8; ++d) sum += qf[d] * bf2f(kv[d]);
    }
    nPs[t] = nP;
    S[t] = sum;
  }

  float mx = S[0];
#pragma unroll
  for (int t = 1; t < 9; ++t) mx = fmaxf(mx, S[t]);
  float e[9], tot = 0.f;
#pragma unroll
  for (int t = 0; t < 9; ++t) { e[t] = __expf(S[t] - mx); tot += e[t]; }
  const float inv = 1.0f / tot;

  float of[8] = {0.f, 0.f, 0.f, 0.f, 0.f, 0.f, 0.f, 0.f};
#pragma unroll
  for (int t = 0; t < 9; ++t) {
    if (nPs[t] >= 0) {
      u16x8 vv = *(const u16x8*)&Vb[(size_t)nPs[t] * 256 + c0];
      const float w = e[t] * inv;
#pragma unroll
      for (int d = 0; d < 8; ++d) of[d] += w * bf2f(vv[d]);
    }
  }

  u16x8 res;
#pragma unroll
  for (int d = 0; d < 8; ++d) {
    float v = of[d] * bs[c0 + d] + bb[c0 + d];
    v = fmaxf(v, 0.0f);
    res[d] = f2bf(v);
  }
  *(u16x8*)&O[(size_t)P * 256 + c0] = res;
}

// ---------------------------------------------------------------------------
extern "C" void kernel_launch(void* const* d_in, const int* in_sizes, int n_in,
                              void* d_out, int out_size, void* d_ws, size_t ws_size,
                              hipStream_t stream) {
  (void)in_sizes; (void)n_in; (void)out_size; (void)ws_size;
  const float* x       = (const float*)d_in[0];
  const float* w1      = (const float*)d_in[1];
  const float* bn1_s   = (const float*)d_in[2];
  const float* bn1_b   = (const float*)d_in[3];
  const float* wq      = (const float*)d_in[4];
  const float* bnq_s   = (const float*)d_in[5];
  const float* bnq_b   = (const float*)d_in[6];
  const float* wk      = (const float*)d_in[7];
  const float* bnk_s   = (const float*)d_in[8];
  const float* bnk_b   = (const float*)d_in[9];
  const float* wv      = (const float*)d_in[10];
  const float* bnv_s   = (const float*)d_in[11];
  const float* bnv_b   = (const float*)d_in[12];
  const float* pos_h   = (const float*)d_in[13];
  const float* pos_w   = (const float*)d_in[14];
  const float* bnatt_s = (const float*)d_in[15];
  const float* bnatt_b = (const float*)d_in[16];
  const float* w3      = (const float*)d_in[17];
  const float* bn3_s   = (const float*)d_in[18];
  const float* bn3_b   = (const float*)d_in[19];

  char* ws = (char*)d_ws;
  unsigned short* h1t   = (unsigned short*)(ws);               // 8 MiB
  unsigned short* qkvt  = (unsigned short*)(ws + 8388608);     // 24 MiB (q|k|v)
  unsigned short* att   = (unsigned short*)(ws + 33554432);    // 8 MiB
  unsigned short* xt    = (unsigned short*)(ws + 41943040);    // 32 MiB
  unsigned short* w1b   = (unsigned short*)(ws + 75497472);    // 512 KiB
  unsigned short* wqkvb = (unsigned short*)(ws + 76021760);    // 384 KiB
  unsigned short* w3b   = (unsigned short*)(ws + 76414976);    // 512 KiB
  float*          sqkv  = (float*)(ws + 76939264);             // 3 KiB
  float*          bqkv  = (float*)(ws + 76942336);             // 3 KiB

  // prep: transpose (16384 blocks) + weight convert (2822 blocks)
  k_prep<<<dim3(19206), dim3(256), 0, stream>>>(
      x, xt, w1, wq, wk, wv, w3, bnq_s, bnk_s, bnv_s, bnq_b, bnk_b, bnv_b,
      w1b, wqkvb, w3b, sqkv, bqkv);

  // conv1: M=256, N=16384, K=1024; tile 128x64, BK=64 -> nwg=512, gy=2
  k_gemm_bt<4, 2, 0, 64><<<dim3(512), dim3(256), 0, stream>>>(
      w1b, xt, h1t, bn1_s, bn1_b, nullptr, 1024, 1, 2);

  // fused qkv: stacked A (768x256); tile 128x128, BK=32 -> nwg=768, gy=6
  k_gemm_bt<4, 4, 0, 32><<<dim3(768), dim3(256), 0, stream>>>(
      wqkvb, h1t, qkvt, sqkv, bqkv, nullptr, 256, 3, 6);

  k_attn<<<dim3(2048), dim3(256), 0, stream>>>(
      qkvt, qkvt + 4194304, qkvt + 8388608, att, pos_h, pos_w, bnatt_s, bnatt_b);

  // conv3 + residual(bf16 from xt) + relu -> d_out (f32); tile 128x128,
  // BK=32 -> nwg=1024, gy=8
  k_gemm_bt<4, 4, 1, 32><<<dim3(1024), dim3(256), 0, stream>>>(
      w3b, att, d_out, bn3_s, bn3_b, xt, 256, 0, 8);
}